// Round 8
// baseline (143.858 us; speedup 1.0000x reference)
//
#include <hip/hip_runtime.h>

#define UNITS 64
#define NNODES 50000
#define NBUCK 512          // bucket = row*512/50000, 97-98 rows each
#define CAP 3584           // records per bucket region (mean 3125, sigma ~56 -> +8 sigma)
#define BIN_TPB 1024
#define BIN_EPT 8          // 8192 edges per bin block -> 196 blocks, runs of ~16
#define SPMM_TPB 1024

typedef unsigned long long u64;
typedef unsigned int u32;
typedef unsigned short u16;

// ---------------- workspace layout (bytes) ----------------
// kb      : [0,        6400000)   3.2M bf16 (kernel cast)
// gcursor : [6400000,  6402048)   512 ints
// edges   : [6402048,  6402048 + NBUCK*CAP*8 = 14.68MB)  packed records:
//           bits[63:32]=value(f32), [31:23]=bucket, [22:16]=row-in-bucket, [15:0]=col

__device__ __forceinline__ int rowbase_of(u32 b) {
    return (int)((b * 50000u + 511u) >> 9);   // ceil(b*50000/512)
}

// f32 -> bf16 (RN) convert, fused with gcursor init
__global__ void gc_prep(const float* __restrict__ kf, u16* __restrict__ kb,
                        int* __restrict__ gcursor, int n4) {
    int i = blockIdx.x * blockDim.x + threadIdx.x;
    if (blockIdx.x == 0 && threadIdx.x < 256) {
        gcursor[threadIdx.x]       = threadIdx.x * CAP;
        gcursor[threadIdx.x + 256] = (threadIdx.x + 256) * CAP;
    }
    if (i >= n4) return;
    float4 f = ((const float4*)kf)[i];
    ushort4 o;
    u32 b;
    b = __float_as_uint(f.x); o.x = (u16)((b + 0x7FFFu + ((b >> 16) & 1u)) >> 16);
    b = __float_as_uint(f.y); o.y = (u16)((b + 0x7FFFu + ((b >> 16) & 1u)) >> 16);
    b = __float_as_uint(f.z); o.z = (u16)((b + 0x7FFFu + ((b >> 16) & 1u)) >> 16);
    b = __float_as_uint(f.w); o.w = (u16)((b + 0x7FFFu + ((b >> 16) & 1u)) >> 16);
    ((ushort4*)kb)[i] = o;
}

// Bin edges into padded per-bucket regions with coalesced writes.
__global__ __launch_bounds__(BIN_TPB) void gc_bin(const int* __restrict__ rows,
                                                  const int* __restrict__ cols,
                                                  const float* __restrict__ values,
                                                  int* __restrict__ gcursor,
                                                  u64* __restrict__ edges, int nnz) {
    __shared__ u64 stage[BIN_TPB * BIN_EPT];   // 64 KB
    __shared__ int hist[NBUCK];
    __shared__ int lstart[NBUCK];
    __shared__ int delta[NBUCK];
    __shared__ int wsum[8];
    int t = threadIdx.x;
    if (t < NBUCK) hist[t] = 0;
    __syncthreads();

    int blockStart = blockIdx.x * (BIN_TPB * BIN_EPT);
    int cnt = min(BIN_TPB * BIN_EPT, nnz - blockStart);

    u64 rec[BIN_EPT];
    int bk[BIN_EPT];
    int rk[BIN_EPT];
#pragma unroll
    for (int k = 0; k < BIN_EPT; ++k) {
        int idx = blockStart + k * BIN_TPB + t;
        if (idx < nnz) {
            int r = rows[idx];
            u32 c = (u32)cols[idx];
            u32 v = __float_as_uint(values[idx]);
            int b = (int)(((u32)r * 512u) / 50000u);
            int lrow = r - rowbase_of((u32)b);
            rec[k] = ((u64)v << 32) | ((u64)(u32)b << 23) | ((u64)(u32)lrow << 16) | (u64)c;
            bk[k] = b;
            rk[k] = atomicAdd(&hist[b], 1);   // int LDS atomic: native ds_add
        } else {
            bk[k] = -1;
        }
    }
    __syncthreads();

    // shuffle-based exclusive scan of hist[0..512) -> lstart
    {
        int wid = t >> 6, ln = t & 63;
        int val = (t < NBUCK) ? hist[t] : 0;
        if (wid < 8) {
            for (int off = 1; off < 64; off <<= 1) {
                int x = __shfl_up(val, off, 64);
                if (ln >= off) val += x;
            }
            if (ln == 63) wsum[wid] = val;
        }
        __syncthreads();
        if (t == 0) {
            int s = 0;
            for (int i = 0; i < 8; ++i) { int x = wsum[i]; wsum[i] = s; s += x; }
        }
        __syncthreads();
        if (wid < 8) {
            int incl = val + wsum[wid];
            int excl = incl - hist[t];
            int h = hist[t];
            int gbase = (h > 0) ? atomicAdd(&gcursor[t], h) : 0;
            delta[t] = gbase - excl;
            lstart[t] = excl;
        }
    }
    __syncthreads();

#pragma unroll
    for (int k = 0; k < BIN_EPT; ++k) {
        if (bk[k] >= 0) stage[lstart[bk[k]] + rk[k]] = rec[k];
    }
    __syncthreads();

    for (int i = t; i < cnt; i += BIN_TPB) {
        u64 r = stage[i];
        int b = (int)((r >> 23) & 0x1FF);
        int gpos = delta[b] + i;
        if (gpos < (b + 1) * CAP) edges[gpos] = r;   // overflow insurance
    }
}

// One block per bucket. Phase 1: coalesced record load into registers +
// int-LDS-atomic rank. Phase 2: shuffle scan of row hist. Phase 3: scatter
// into LDS at row-sorted position. Phase 4: pair-processing accumulation —
// lane&31 = unit pair (u32 bf16x2 load), lane>>5 = edge parity; shfl_xor
// combine; float2 store with fused bias+relu.
__global__ __launch_bounds__(SPMM_TPB) void gc_spmm(const u64* __restrict__ edges,
                                                    const int* __restrict__ gcursor,
                                                    const u16* __restrict__ kb,
                                                    const float* __restrict__ bias,
                                                    float* __restrict__ out) {
    __shared__ u64 stage[CAP];        // 28.7 KB
    __shared__ int rhist[128];
    __shared__ int rstart[129];
    __shared__ int wsum2[2];
    int b = blockIdx.x;
    int t = threadIdx.x;
    int rowlo = rowbase_of((u32)b);
    int nrows = rowbase_of((u32)b + 1u) - rowlo;   // 97 or 98
    int count = min(gcursor[b] - b * CAP, CAP);
    const u64* eb = edges + (size_t)b * CAP;

    if (t < 128) rhist[t] = 0;
    __syncthreads();

    // Phase 1: load + rank (records stay in registers)
    u64 rec[4];
    int rk[4], lr[4];
#pragma unroll
    for (int k = 0; k < 4; ++k) {
        int i = k * SPMM_TPB + t;
        if (i < count) {
            u64 r = eb[i];
            rec[k] = r;
            int l = (int)((r >> 16) & 0x7F);
            lr[k] = l;
            rk[k] = atomicAdd(&rhist[l], 1);
        } else {
            lr[k] = -1;
        }
    }
    __syncthreads();

    // Phase 2: shuffle-based exclusive scan of rhist[0..128) -> rstart
    {
        int wid = t >> 6, ln = t & 63;
        int val = (t < 128) ? rhist[t] : 0;
        if (wid < 2) {
            for (int off = 1; off < 64; off <<= 1) {
                int x = __shfl_up(val, off, 64);
                if (ln >= off) val += x;
            }
            if (ln == 63) wsum2[wid] = val;
        }
        __syncthreads();
        if (t == 0) { int a = wsum2[0]; wsum2[0] = 0; wsum2[1] = a; }
        __syncthreads();
        if (wid < 2) rstart[t] = val + wsum2[wid] - rhist[t];
        if (t == 0) rstart[128] = count;
    }
    __syncthreads();

    // Phase 3: scatter to row-sorted LDS positions
#pragma unroll
    for (int k = 0; k < 4; ++k) {
        if (lr[k] >= 0) stage[rstart[lr[k]] + rk[k]] = rec[k];
    }
    __syncthreads();

    // Phase 4: 16 waves; wave handles rows w, w+16, ...; 2 edges per iteration
    int lane = t & 63;
    int half = lane >> 5;            // which edge of the pair
    int ul = lane & 31;              // unit-pair index: units 2*ul, 2*ul+1
    int w = t >> 6;
    float2 bl = ((const float2*)bias)[ul];

    for (int row = w; row < nrows; row += 16) {
        int j0 = rstart[row];
        int e  = rstart[row + 1];
        int npairs = (e - j0 + 1) >> 1;
        float ax = 0.0f, ay = 0.0f;
        for (int p = 0; p < npairs; ++p) {
            int j = j0 + 2 * p + half;
            float v = 0.0f, kx = 0.0f, ky = 0.0f;
            if (j < e) {
                u64 r = stage[j];
                u32 kk = *(const u32*)(kb + ((u32)r & 0xFFFFu) * UNITS + 2 * ul);
                kx = __uint_as_float(kk << 16);
                ky = __uint_as_float(kk & 0xFFFF0000u);
                v = __uint_as_float((u32)(r >> 32));
            }
            ax = fmaf(v, kx, ax);
            ay = fmaf(v, ky, ay);
        }
        ax += __shfl_xor(ax, 32, 64);
        ay += __shfl_xor(ay, 32, 64);
        if (half == 0) {
            float2 o;
            o.x = fmaxf(ax + bl.x, 0.0f);
            o.y = fmaxf(ay + bl.y, 0.0f);
            ((float2*)out)[(size_t)(rowlo + row) * 32 + ul] = o;
        }
    }
}

extern "C" void kernel_launch(void* const* d_in, const int* in_sizes, int n_in,
                              void* d_out, int out_size, void* d_ws, size_t ws_size,
                              hipStream_t stream) {
    const int*   rows   = (const int*)d_in[0];
    const int*   cols   = (const int*)d_in[1];
    const float* values = (const float*)d_in[2];
    const float* kern   = (const float*)d_in[3];
    const float* bias   = (const float*)d_in[4];
    float* out = (float*)d_out;

    const int nnz = in_sizes[0];

    char* ws = (char*)d_ws;
    u16* kb      = (u16*)(ws + 0);
    int* gcursor = (int*)(ws + 6400000);
    u64* edges   = (u64*)(ws + 6402048);

    int n4 = (NNODES * UNITS) / 4;  // 800000
    gc_prep<<<(n4 + 255) / 256, 256, 0, stream>>>(kern, kb, gcursor, n4);

    gc_bin<<<(nnz + BIN_TPB * BIN_EPT - 1) / (BIN_TPB * BIN_EPT), BIN_TPB, 0, stream>>>(
        rows, cols, values, gcursor, edges, nnz);

    gc_spmm<<<NBUCK, SPMM_TPB, 0, stream>>>(edges, gcursor, kb, bias, out);
}

// Round 9
// 125.517 us; speedup vs baseline: 1.1461x; 1.1461x over previous
//
#include <hip/hip_runtime.h>

#define UNITS 64
#define NNODES 50000
#define NBUCK 512          // bucket = row*512/50000, 97-98 rows each
#define CAP 3584           // records per bucket region (mean 3125, sigma ~56 -> +8 sigma)
#define BIN_TPB 512
#define BIN_EPT 8          // 4096 edges per bin block -> 391 blocks
#define SPMM_TPB 1024

typedef unsigned long long u64;
typedef unsigned int u32;
typedef unsigned short u16;

// ---------------- workspace layout (bytes) ----------------
// kb      : [0,        6400000)   3.2M bf16 (kernel cast)
// gcursor : [6400000,  6402048)   512 ints
// edges   : [6402048,  6402048 + NBUCK*CAP*8 = 14.68MB)  packed records:
//           bits[63:32]=value(f32), [31:23]=bucket, [22:16]=row-in-bucket, [15:0]=col

__device__ __forceinline__ int rowbase_of(u32 b) {
    return (int)((b * 50000u + 511u) >> 9);   // ceil(b*50000/512)
}

// f32 -> bf16 (RN) convert, fused with gcursor init
__global__ void gc_prep(const float* __restrict__ kf, u16* __restrict__ kb,
                        int* __restrict__ gcursor, int n4) {
    int i = blockIdx.x * blockDim.x + threadIdx.x;
    if (blockIdx.x == 0 && threadIdx.x < 256) {
        gcursor[threadIdx.x]       = threadIdx.x * CAP;
        gcursor[threadIdx.x + 256] = (threadIdx.x + 256) * CAP;
    }
    if (i >= n4) return;
    float4 f = ((const float4*)kf)[i];
    ushort4 o;
    u32 b;
    b = __float_as_uint(f.x); o.x = (u16)((b + 0x7FFFu + ((b >> 16) & 1u)) >> 16);
    b = __float_as_uint(f.y); o.y = (u16)((b + 0x7FFFu + ((b >> 16) & 1u)) >> 16);
    b = __float_as_uint(f.z); o.z = (u16)((b + 0x7FFFu + ((b >> 16) & 1u)) >> 16);
    b = __float_as_uint(f.w); o.w = (u16)((b + 0x7FFFu + ((b >> 16) & 1u)) >> 16);
    ((ushort4*)kb)[i] = o;
}

// Bin edges into padded per-bucket regions with coalesced writes.
__global__ __launch_bounds__(BIN_TPB) void gc_bin(const int* __restrict__ rows,
                                                  const int* __restrict__ cols,
                                                  const float* __restrict__ values,
                                                  int* __restrict__ gcursor,
                                                  u64* __restrict__ edges, int nnz) {
    __shared__ u64 stage[BIN_TPB * BIN_EPT];   // 32 KB
    __shared__ int hist[NBUCK];
    __shared__ int lstart[NBUCK];
    __shared__ int delta[NBUCK];
    __shared__ int wsum[8];
    int t = threadIdx.x;
    if (t < NBUCK) hist[t] = 0;
    __syncthreads();

    int blockStart = blockIdx.x * (BIN_TPB * BIN_EPT);
    int cnt = min(BIN_TPB * BIN_EPT, nnz - blockStart);

    u64 rec[BIN_EPT];
    int bk[BIN_EPT];
    int rk[BIN_EPT];
#pragma unroll
    for (int k = 0; k < BIN_EPT; ++k) {
        int idx = blockStart + k * BIN_TPB + t;
        if (idx < nnz) {
            int r = rows[idx];
            u32 c = (u32)cols[idx];
            u32 v = __float_as_uint(values[idx]);
            int b = (int)(((u32)r * 512u) / 50000u);
            int lrow = r - rowbase_of((u32)b);
            rec[k] = ((u64)v << 32) | ((u64)(u32)b << 23) | ((u64)(u32)lrow << 16) | (u64)c;
            bk[k] = b;
            rk[k] = atomicAdd(&hist[b], 1);   // int LDS atomic: native ds_add
        } else {
            bk[k] = -1;
        }
    }
    __syncthreads();

    // shuffle-based exclusive scan of hist[0..512) -> lstart (8 waves x 64)
    {
        int wid = t >> 6, ln = t & 63;
        int val = hist[t];
        for (int off = 1; off < 64; off <<= 1) {
            int x = __shfl_up(val, off, 64);
            if (ln >= off) val += x;
        }
        if (ln == 63) wsum[wid] = val;
        __syncthreads();
        if (t == 0) {
            int s = 0;
            for (int i = 0; i < 8; ++i) { int x = wsum[i]; wsum[i] = s; s += x; }
        }
        __syncthreads();
        int incl = val + wsum[wid];
        int excl = incl - hist[t];
        int h = hist[t];
        int gbase = (h > 0) ? atomicAdd(&gcursor[t], h) : 0;
        delta[t] = gbase - excl;
        lstart[t] = excl;
    }
    __syncthreads();

#pragma unroll
    for (int k = 0; k < BIN_EPT; ++k) {
        if (bk[k] >= 0) stage[lstart[bk[k]] + rk[k]] = rec[k];
    }
    __syncthreads();

    for (int i = t; i < cnt; i += BIN_TPB) {
        u64 r = stage[i];
        int b = (int)((r >> 23) & 0x1FF);
        int gpos = delta[b] + i;
        if (gpos < (b + 1) * CAP) edges[gpos] = r;   // overflow insurance
    }
}

// One block per bucket. Phases 1-3 build a row-sorted record list in LDS.
// Phase 4: pair layout (lane&31 = unit pair, lane>>5 = edge parity) with x4
// unroll -> 8 edges / 4 independent kb loads in flight per lane.
__global__ __launch_bounds__(SPMM_TPB) void gc_spmm(const u64* __restrict__ edges,
                                                    const int* __restrict__ gcursor,
                                                    const u16* __restrict__ kb,
                                                    const float* __restrict__ bias,
                                                    float* __restrict__ out) {
    __shared__ u64 stage[CAP];        // 28.7 KB
    __shared__ int rhist[128];
    __shared__ int rstart[129];
    __shared__ int wsum2[2];
    int b = blockIdx.x;
    int t = threadIdx.x;
    int rowlo = rowbase_of((u32)b);
    int nrows = rowbase_of((u32)b + 1u) - rowlo;   // 97 or 98
    int count = min(gcursor[b] - b * CAP, CAP);
    const u64* eb = edges + (size_t)b * CAP;

    if (t < 128) rhist[t] = 0;
    __syncthreads();

    // Phase 1: load + rank (records stay in registers)
    u64 rec[4];
    int rk[4], lr[4];
#pragma unroll
    for (int k = 0; k < 4; ++k) {
        int i = k * SPMM_TPB + t;
        if (i < count) {
            u64 r = eb[i];
            rec[k] = r;
            int l = (int)((r >> 16) & 0x7F);
            lr[k] = l;
            rk[k] = atomicAdd(&rhist[l], 1);
        } else {
            lr[k] = -1;
        }
    }
    __syncthreads();

    // Phase 2: shuffle-based exclusive scan of rhist[0..128) -> rstart
    {
        int wid = t >> 6, ln = t & 63;
        int val = (t < 128) ? rhist[t] : 0;
        if (wid < 2) {
            for (int off = 1; off < 64; off <<= 1) {
                int x = __shfl_up(val, off, 64);
                if (ln >= off) val += x;
            }
            if (ln == 63) wsum2[wid] = val;
        }
        __syncthreads();
        if (t == 0) { int a = wsum2[0]; wsum2[0] = 0; wsum2[1] = a; }
        __syncthreads();
        if (wid < 2) rstart[t] = val + wsum2[wid] - rhist[t];
        if (t == 0) rstart[128] = count;
    }
    __syncthreads();

    // Phase 3: scatter to row-sorted LDS positions
#pragma unroll
    for (int k = 0; k < 4; ++k) {
        if (lr[k] >= 0) stage[rstart[lr[k]] + rk[k]] = rec[k];
    }
    __syncthreads();

    // Phase 4: 16 waves; wave handles rows w, w+16, ...
    int lane = t & 63;
    int half = lane >> 5;            // edge parity within a pair step
    int ul = lane & 31;              // unit-pair index: units 2*ul, 2*ul+1
    int w = t >> 6;
    float2 bl = ((const float2*)bias)[ul];

    for (int row = w; row < nrows; row += 16) {
        int j0 = rstart[row];
        int e  = rstart[row + 1];
        float ax0 = 0.f, ay0 = 0.f, ax1 = 0.f, ay1 = 0.f;
        float ax2 = 0.f, ay2 = 0.f, ax3 = 0.f, ay3 = 0.f;
        int j = j0;
        // main loop: 8 edges per iteration, branch-free, 4 loads in flight
        for (; j + 8 <= e; j += 8) {
            u64 r0 = stage[j + 0 + half];
            u64 r1 = stage[j + 2 + half];
            u64 r2 = stage[j + 4 + half];
            u64 r3 = stage[j + 6 + half];
            u32 kk0 = *(const u32*)(kb + ((u32)r0 & 0xFFFFu) * UNITS + 2 * ul);
            u32 kk1 = *(const u32*)(kb + ((u32)r1 & 0xFFFFu) * UNITS + 2 * ul);
            u32 kk2 = *(const u32*)(kb + ((u32)r2 & 0xFFFFu) * UNITS + 2 * ul);
            u32 kk3 = *(const u32*)(kb + ((u32)r3 & 0xFFFFu) * UNITS + 2 * ul);
            float v0 = __uint_as_float((u32)(r0 >> 32));
            float v1 = __uint_as_float((u32)(r1 >> 32));
            float v2 = __uint_as_float((u32)(r2 >> 32));
            float v3 = __uint_as_float((u32)(r3 >> 32));
            ax0 = fmaf(v0, __uint_as_float(kk0 << 16), ax0);
            ay0 = fmaf(v0, __uint_as_float(kk0 & 0xFFFF0000u), ay0);
            ax1 = fmaf(v1, __uint_as_float(kk1 << 16), ax1);
            ay1 = fmaf(v1, __uint_as_float(kk1 & 0xFFFF0000u), ay1);
            ax2 = fmaf(v2, __uint_as_float(kk2 << 16), ax2);
            ay2 = fmaf(v2, __uint_as_float(kk2 & 0xFFFF0000u), ay2);
            ax3 = fmaf(v3, __uint_as_float(kk3 << 16), ax3);
            ay3 = fmaf(v3, __uint_as_float(kk3 & 0xFFFF0000u), ay3);
        }
        // pairwise tail
        for (; j < e; j += 2) {
            int ji = j + half;
            float v = 0.f, kx = 0.f, ky = 0.f;
            if (ji < e) {
                u64 r = stage[ji];
                u32 kk = *(const u32*)(kb + ((u32)r & 0xFFFFu) * UNITS + 2 * ul);
                kx = __uint_as_float(kk << 16);
                ky = __uint_as_float(kk & 0xFFFF0000u);
                v = __uint_as_float((u32)(r >> 32));
            }
            ax0 = fmaf(v, kx, ax0);
            ay0 = fmaf(v, ky, ay0);
        }
        float ax = (ax0 + ax1) + (ax2 + ax3);
        float ay = (ay0 + ay1) + (ay2 + ay3);
        ax += __shfl_xor(ax, 32, 64);
        ay += __shfl_xor(ay, 32, 64);
        if (half == 0) {
            float2 o;
            o.x = fmaxf(ax + bl.x, 0.0f);
            o.y = fmaxf(ay + bl.y, 0.0f);
            ((float2*)out)[(size_t)(rowlo + row) * 32 + ul] = o;
        }
    }
}

extern "C" void kernel_launch(void* const* d_in, const int* in_sizes, int n_in,
                              void* d_out, int out_size, void* d_ws, size_t ws_size,
                              hipStream_t stream) {
    const int*   rows   = (const int*)d_in[0];
    const int*   cols   = (const int*)d_in[1];
    const float* values = (const float*)d_in[2];
    const float* kern   = (const float*)d_in[3];
    const float* bias   = (const float*)d_in[4];
    float* out = (float*)d_out;

    const int nnz = in_sizes[0];

    char* ws = (char*)d_ws;
    u16* kb      = (u16*)(ws + 0);
    int* gcursor = (int*)(ws + 6400000);
    u64* edges   = (u64*)(ws + 6402048);

    int n4 = (NNODES * UNITS) / 4;  // 800000
    gc_prep<<<(n4 + 255) / 256, 256, 0, stream>>>(kern, kb, gcursor, n4);

    gc_bin<<<(nnz + BIN_TPB * BIN_EPT - 1) / (BIN_TPB * BIN_EPT), BIN_TPB, 0, stream>>>(
        rows, cols, values, gcursor, edges, nnz);

    gc_spmm<<<NBUCK, SPMM_TPB, 0, stream>>>(edges, gcursor, kb, bias, out);
}